// Round 5
// baseline (200.966 us; speedup 1.0000x reference)
//
#include <hip/hip_runtime.h>

// KANLayer: B=1024, I=64, O=64, H=32. ALL I/O float32 (per reference).
// out[b,o] = sum_i [ bw[o,i]*leaky(x[b,i]) + lw[o,i]*( sum_k W3[o,i,k]*h2[k] + b3[o,i] ) ]
//   h1[h] = leaky(x[b,i]*W1[o,i,h] + b1[o,i,h])
//   h2[k] = leaky(sum_h h1[h]*W2[o,i,k,h] + b2[o,i,k])
//
// R5: single kernel, R2-proven memory pattern (W2 B-frags straight from
// global each iter, NO in-loop LDS staging / barriers — R4's in-loop
// double-buffer loop is the prime suspect for its SIGABRT). VALU cut via:
// v_cvt_pkrtz W2 f32->f16 (8 instrs / 2 frags), packed v_pk_fma_f16 h1
// build (MFMA-ready A-frag), W1/b1 pre-converted to f16 LDS once per
// block. mfma_f32_16x16x32_f16, f32 accumulation, b2 folded into C.
// Grid o-fastest: blockIdx.x%8 = XCD -> one W2 slab (256KB f32) per 16
// batch-blocks stays XCD-L2-resident.

#define H_   32
#define NI   64
#define NO   64
#define NB   1024
#define ROWS 64     // batch rows per block; 4 waves x 1 m-tile
#define XS   68     // x LDS row stride (floats): 16B-aligned rows, benign banks

typedef float    floatx4 __attribute__((ext_vector_type(4)));
typedef _Float16 halfx8  __attribute__((ext_vector_type(8)));
typedef _Float16 halfx2  __attribute__((ext_vector_type(2)));

union H8 { halfx8 v8; halfx2 v2[4]; unsigned int u[4]; };

__device__ inline float leaky(float v) { return fmaxf(v, 0.01f * v); }

__device__ inline unsigned int pkrtz(float a, float b) {   // (a,b) -> f16x2, RTZ
    return __builtin_bit_cast(unsigned int, __builtin_amdgcn_cvt_pkrtz(a, b));
}

__global__ __launch_bounds__(256, 4)
void kan_kernel(const float* __restrict__ x,  const float* __restrict__ W1,
                const float* __restrict__ b1, const float* __restrict__ W2,
                const float* __restrict__ b2, const float* __restrict__ W3,
                const float* __restrict__ b3, const float* __restrict__ lw,
                const float* __restrict__ bw, float* __restrict__ out)
{
    __shared__ float    xs[ROWS * XS];     // 17.4 KB, f32 x tile
    __shared__ _Float16 w1s[NI * H_];      // 4 KB
    __shared__ _Float16 b1s[NI * H_];      // 4 KB
    __shared__ float    rc[ROWS];

    const int t    = threadIdx.x;
    const int o    = blockIdx.x;           // o fastest -> same-o blocks share an XCD
    const int row0 = blockIdx.y * ROWS;

    // ---- stage x[row0..row0+63][0..63] (f32, coalesced 16B) ----
    const float* xsrc = x + (size_t)row0 * NI;
    #pragma unroll
    for (int v = 0; v < 4; ++v) {
        int fe = (v * 256 + t) * 4;
        int r = fe >> 6, c = fe & 63;
        *(float4*)(&xs[r * XS + c]) = *(const float4*)(xsrc + fe);
    }
    // ---- stage W1/b1 for this o as f16 (once per block, RTZ pack) ----
    const float* w1g = W1 + (size_t)o * NI * H_;
    const float* b1g = b1 + (size_t)o * NI * H_;
    #pragma unroll
    for (int v = 0; v < 2; ++v) {
        int e = (v * 256 + t) * 4;
        float4 a = *(const float4*)(w1g + e);
        float4 c = *(const float4*)(b1g + e);
        uint2 pa = { pkrtz(a.x, a.y), pkrtz(a.z, a.w) };
        uint2 pc = { pkrtz(c.x, c.y), pkrtz(c.z, c.w) };
        *(uint2*)(w1s + e) = pa;
        *(uint2*)(b1s + e) = pc;
    }
    __syncthreads();

    // ---- per-row constants: rc[r] = sum_i [ bw*leaky(x) + lw*b3 ] ----
    if (t < ROWS) {
        float s = 0.f;
        const float* bwp = bw + o * NI;
        const float* lp  = lw + o * NI;
        const float* b3p = b3 + o * NI;
        for (int i = 0; i < NI; ++i)
            s += bwp[i] * leaky(xs[t * XS + i]) + lp[i] * b3p[i];
        rc[t] = s;
    }

    const int lane = t & 63, wave = t >> 6;
    const int col  = lane & 15;            // MFMA n-index (h2 k-slot)
    const int kh   = lane >> 4;            // contraction quad
    const int koff = kh * 8;
    const int wrow = wave * 16;

    const float* w2p0 = W2 + ((size_t)o * NI * H_ + col) * H_ + koff;
    const float* w2p1 = w2p0 + 16 * H_;
    const float* b2p  = b2 + (size_t)o * NI * H_ + col;
    const float* w3p  = W3 + (size_t)o * NI * H_ + col;
    const float* lwp  = lw + o * NI;
    const float* xrow = xs + (wrow + col) * XS;
    const halfx2 slope = { (_Float16)0.01f, (_Float16)0.01f };

    floatx4 pacc = {0.f, 0.f, 0.f, 0.f};

    #pragma unroll 2
    for (int i = 0; i < NI; ++i) {
        // B-frags: W2[o,i, col(+16), koff..koff+7], f32 -> f16 via pkrtz
        floatx4 a0 = *(const floatx4*)(w2p0);
        floatx4 a1 = *(const floatx4*)(w2p0 + 4);
        floatx4 a2 = *(const floatx4*)(w2p1);
        floatx4 a3 = *(const floatx4*)(w2p1 + 4);
        H8 bf0, bf1;
        bf0.u[0] = pkrtz(a0[0], a0[1]);  bf0.u[1] = pkrtz(a0[2], a0[3]);
        bf0.u[2] = pkrtz(a1[0], a1[1]);  bf0.u[3] = pkrtz(a1[2], a1[3]);
        bf1.u[0] = pkrtz(a2[0], a2[1]);  bf1.u[1] = pkrtz(a2[2], a2[3]);
        bf1.u[2] = pkrtz(a3[0], a3[1]);  bf1.u[3] = pkrtz(a3[2], a3[3]);

        // A-frag: h1 for batch row (wrow+col), h-chunk koff..+7, packed f16
        H8 w1v, b1v, af;
        w1v.v8 = *(const halfx8*)(w1s + i * H_ + koff);
        b1v.v8 = *(const halfx8*)(b1s + i * H_ + koff);
        float xv = xrow[i];
        halfx2 xx = __builtin_bit_cast(halfx2, __builtin_amdgcn_cvt_pkrtz(xv, xv));
        #pragma unroll
        for (int j = 0; j < 4; ++j) {
            halfx2 h = __builtin_elementwise_fma(xx, w1v.v2[j], b1v.v2[j]);
            af.v2[j] = __builtin_elementwise_max(h, h * slope);   // packed leaky
        }

        float lwv  = lwp[i];                          // uniform -> scalar load
        float b2c0 = b2p[0],         b2c1 = b2p[16];
        float w3e0 = lwv * w3p[0],   w3e1 = lwv * w3p[16];

        floatx4 c0 = { b2c0, b2c0, b2c0, b2c0 };      // b2 folded into C
        floatx4 c1 = { b2c1, b2c1, b2c1, b2c1 };
        c0 = __builtin_amdgcn_mfma_f32_16x16x32_f16(af.v8, bf0.v8, c0, 0, 0, 0);
        c1 = __builtin_amdgcn_mfma_f32_16x16x32_f16(af.v8, bf1.v8, c1, 0, 0, 0);

        #pragma unroll
        for (int r = 0; r < 4; ++r)
            pacc[r] += leaky(c0[r]) * w3e0 + leaky(c1[r]) * w3e1;

        w2p0 += H_ * H_;  w2p1 += H_ * H_;
        b2p  += H_;       w3p  += H_;
    }

    __syncthreads();   // rc (written by wave 0) visible to all waves

    // ---- reduce over the 16 column-lanes (k of h2), write out[b,o] ----
    #pragma unroll
    for (int r = 0; r < 4; ++r) {
        float v = pacc[r];
        v += __shfl_xor(v, 1, 64);
        v += __shfl_xor(v, 2, 64);
        v += __shfl_xor(v, 4, 64);
        v += __shfl_xor(v, 8, 64);
        if (col == 0) {
            int rl = wrow + kh * 4 + r;               // C-layout: row=(lane>>4)*4+reg
            out[(size_t)(row0 + rl) * NO + o] = v + rc[rl];
        }
    }
}

extern "C" void kernel_launch(void* const* d_in, const int* in_sizes, int n_in,
                              void* d_out, int out_size, void* d_ws, size_t ws_size,
                              hipStream_t stream) {
    const float* x  = (const float*)d_in[0];
    const float* W1 = (const float*)d_in[1];
    const float* b1 = (const float*)d_in[2];
    const float* W2 = (const float*)d_in[3];
    const float* b2 = (const float*)d_in[4];
    const float* W3 = (const float*)d_in[5];
    const float* b3 = (const float*)d_in[6];
    const float* lw = (const float*)d_in[7];
    const float* bw = (const float*)d_in[8];
    float* out = (float*)d_out;

    dim3 grid(NO, NB / ROWS);   // 1024 blocks, o fastest
    kan_kernel<<<grid, dim3(256), 0, stream>>>(x, W1, b1, W2, b2, W3, b3, lw, bw, out);
}

// Round 6
// 116.140 us; speedup vs baseline: 1.7304x; 1.7304x over previous
//
#include <hip/hip_runtime.h>

// KANLayer: B=1024, I=64, O=64, H=32. ALL I/O float32 (per reference).
// out[b,o] = sum_i [ bw[o,i]*leaky(x[b,i]) + lw[o,i]*( sum_k W3[o,i,k]*h2[k] + b3[o,i] ) ]
//   h1[h] = leaky(x[b,i]*W1[o,i,h] + b1[o,i,h])
//   h2[k] = leaky(sum_h h1[h]*W2[o,i,k,h] + b2[o,i,k])
//
// R6: i-split waves. Block = one o x 64 batch rows; wave w owns i-slice
// [w*16, w*16+16) and computes ALL 4 m-tiles (64 rows) for it. Per W2
// fragment loaded we now run 8 MFMAs (vs 2 in R5): 4x less L2 traffic
// (1 GB -> 256 MB) and ~4x more compute per load to hide L2 latency —
// R5 was latency-bound (VALU 22%, Mfma 2.5%, HBM 1%). Cross-wave i-partials
// reduced through LDS part[4][64] after one barrier. No in-loop barriers,
// no workspace. mfma_f32_16x16x32_f16, f32 accumulation, b2 folded into C.

#define H_   32
#define NI   64
#define NO   64
#define NB   1024
#define ROWS 64     // batch rows per block
#define XS   68     // x LDS row stride (floats)

typedef float    floatx4 __attribute__((ext_vector_type(4)));
typedef _Float16 halfx8  __attribute__((ext_vector_type(8)));
typedef _Float16 halfx2  __attribute__((ext_vector_type(2)));

union H8 { halfx8 v8; halfx2 v2[4]; unsigned int u[4]; };

__device__ inline float leaky(float v) { return fmaxf(v, 0.01f * v); }

__device__ inline unsigned int pkrtz(float a, float b) {   // (a,b) -> f16x2, RTZ
    return __builtin_bit_cast(unsigned int, __builtin_amdgcn_cvt_pkrtz(a, b));
}

__global__ __launch_bounds__(256, 4)
void kan_kernel(const float* __restrict__ x,  const float* __restrict__ W1,
                const float* __restrict__ b1, const float* __restrict__ W2,
                const float* __restrict__ b2, const float* __restrict__ W3,
                const float* __restrict__ b3, const float* __restrict__ lw,
                const float* __restrict__ bw, float* __restrict__ out)
{
    __shared__ float    xs[ROWS * XS];     // 17.4 KB
    __shared__ _Float16 w1s[NI * H_];      // 4 KB
    __shared__ _Float16 b1s[NI * H_];      // 4 KB
    __shared__ float    rc[ROWS];
    __shared__ float    part[4][ROWS];     // per-wave i-slice partials (1 KB)

    const int t    = threadIdx.x;
    const int o    = blockIdx.x;           // o fastest -> same-o blocks share an XCD
    const int row0 = blockIdx.y * ROWS;

    // ---- stage x tile (f32, coalesced 16B) ----
    const float* xsrc = x + (size_t)row0 * NI;
    #pragma unroll
    for (int v = 0; v < 4; ++v) {
        int fe = (v * 256 + t) * 4;
        int r = fe >> 6, c = fe & 63;
        *(float4*)(&xs[r * XS + c]) = *(const float4*)(xsrc + fe);
    }
    // ---- stage W1/b1 for this o as f16 (RTZ pack) ----
    const float* w1g = W1 + (size_t)o * NI * H_;
    const float* b1g = b1 + (size_t)o * NI * H_;
    #pragma unroll
    for (int v = 0; v < 2; ++v) {
        int e = (v * 256 + t) * 4;
        float4 a = *(const float4*)(w1g + e);
        float4 c = *(const float4*)(b1g + e);
        uint2 pa = { pkrtz(a.x, a.y), pkrtz(a.z, a.w) };
        uint2 pc = { pkrtz(c.x, c.y), pkrtz(c.z, c.w) };
        *(uint2*)(w1s + e) = pa;
        *(uint2*)(b1s + e) = pc;
    }
    __syncthreads();

    // ---- per-row constants: rc[r] = sum_i [ bw*leaky(x) + lw*b3 ] ----
    if (t < ROWS) {
        float s = 0.f;
        const float* bwp = bw + o * NI;
        const float* lp  = lw + o * NI;
        const float* b3p = b3 + o * NI;
        for (int i = 0; i < NI; ++i)
            s += bwp[i] * leaky(xs[t * XS + i]) + lp[i] * b3p[i];
        rc[t] = s;
    }

    const int lane = t & 63, wave = t >> 6;
    const int col  = lane & 15;            // MFMA n-index (h2 k-slot) / A m-offset
    const int kh   = lane >> 4;            // contraction quad
    const int koff = kh * 8;
    const int i0   = wave * 16;            // this wave's i-slice

    const float* w2p0 = W2 + ((size_t)(o * NI + i0) * H_ + col) * H_ + koff;
    const float* w2p1 = w2p0 + 16 * H_;
    const float* b2p  = b2 + (size_t)(o * NI + i0) * H_ + col;
    const float* w3p  = W3 + (size_t)(o * NI + i0) * H_ + col;
    const float* lwp  = lw + o * NI + i0;
    const halfx2 slope = { (_Float16)0.01f, (_Float16)0.01f };

    floatx4 pacc[4] = { {0,0,0,0}, {0,0,0,0}, {0,0,0,0}, {0,0,0,0} };

    #pragma unroll 2
    for (int ii = 0; ii < 16; ++ii) {
        const int i = i0 + ii;

        // B-frags: W2[o,i, col(+16), koff..+7], f32 -> f16 via pkrtz
        floatx4 a0 = *(const floatx4*)(w2p0);
        floatx4 a1 = *(const floatx4*)(w2p0 + 4);
        floatx4 a2 = *(const floatx4*)(w2p1);
        floatx4 a3 = *(const floatx4*)(w2p1 + 4);
        H8 bf0, bf1;
        bf0.u[0] = pkrtz(a0[0], a0[1]);  bf0.u[1] = pkrtz(a0[2], a0[3]);
        bf0.u[2] = pkrtz(a1[0], a1[1]);  bf0.u[3] = pkrtz(a1[2], a1[3]);
        bf1.u[0] = pkrtz(a2[0], a2[1]);  bf1.u[1] = pkrtz(a2[2], a2[3]);
        bf1.u[2] = pkrtz(a3[0], a3[1]);  bf1.u[3] = pkrtz(a3[2], a3[3]);

        H8 w1v, b1v;
        w1v.v8 = *(const halfx8*)(w1s + i * H_ + koff);
        b1v.v8 = *(const halfx8*)(b1s + i * H_ + koff);

        float lwv  = lwp[ii];                       // uniform -> scalar load
        float b2c0 = b2p[0],       b2c1 = b2p[16];
        float w3e0 = lwv * w3p[0], w3e1 = lwv * w3p[16];

        #pragma unroll
        for (int m = 0; m < 4; ++m) {
            float xv = xs[(m * 16 + col) * XS + i];
            halfx2 xx = __builtin_bit_cast(halfx2,
                            __builtin_amdgcn_cvt_pkrtz(xv, xv));
            H8 af;
            #pragma unroll
            for (int j = 0; j < 4; ++j) {
                halfx2 h = __builtin_elementwise_fma(xx, w1v.v2[j], b1v.v2[j]);
                af.v2[j] = __builtin_elementwise_max(h, h * slope);  // pk leaky
            }
            floatx4 c0 = { b2c0, b2c0, b2c0, b2c0 };   // b2 folded into C
            floatx4 c1 = { b2c1, b2c1, b2c1, b2c1 };
            c0 = __builtin_amdgcn_mfma_f32_16x16x32_f16(af.v8, bf0.v8, c0, 0, 0, 0);
            c1 = __builtin_amdgcn_mfma_f32_16x16x32_f16(af.v8, bf1.v8, c1, 0, 0, 0);
            #pragma unroll
            for (int r = 0; r < 4; ++r)
                pacc[m][r] += leaky(c0[r]) * w3e0 + leaky(c1[r]) * w3e1;
        }

        w2p0 += H_ * H_;  w2p1 += H_ * H_;
        b2p  += H_;       w3p  += H_;
    }

    // ---- in-wave reduce over the 16 col lanes, deposit i-slice partials ----
    #pragma unroll
    for (int m = 0; m < 4; ++m) {
        #pragma unroll
        for (int r = 0; r < 4; ++r) {
            float v = pacc[m][r];
            v += __shfl_xor(v, 1, 64);
            v += __shfl_xor(v, 2, 64);
            v += __shfl_xor(v, 4, 64);
            v += __shfl_xor(v, 8, 64);
            if (col == 0)
                part[wave][m * 16 + kh * 4 + r] = v;   // C row = (lane>>4)*4+reg
        }
    }
    __syncthreads();

    // ---- cross-wave sum + per-row constant, write out[b,o] ----
    if (t < ROWS) {
        float v = part[0][t] + part[1][t] + part[2][t] + part[3][t] + rc[t];
        out[(size_t)(row0 + t) * NO + o] = v;
    }
}

extern "C" void kernel_launch(void* const* d_in, const int* in_sizes, int n_in,
                              void* d_out, int out_size, void* d_ws, size_t ws_size,
                              hipStream_t stream) {
    const float* x  = (const float*)d_in[0];
    const float* W1 = (const float*)d_in[1];
    const float* b1 = (const float*)d_in[2];
    const float* W2 = (const float*)d_in[3];
    const float* b2 = (const float*)d_in[4];
    const float* W3 = (const float*)d_in[5];
    const float* b3 = (const float*)d_in[6];
    const float* lw = (const float*)d_in[7];
    const float* bw = (const float*)d_in[8];
    float* out = (float*)d_out;

    dim3 grid(NO, NB / ROWS);   // 1024 blocks, o fastest (XCD-local W2)
    kan_kernel<<<grid, dim3(256), 0, stream>>>(x, W1, b1, W2, b2, W3, b3, lw, bw, out);
}

// Round 7
// 113.021 us; speedup vs baseline: 1.7781x; 1.0276x over previous
//
#include <hip/hip_runtime.h>

// KANLayer: B=1024, I=64, O=64, H=32. ALL I/O float32 (per reference).
// out[b,o] = sum_i [ bw[o,i]*leaky(x[b,i]) + lw[o,i]*( sum_k W3[o,i,k]*h2[k] + b3[o,i] ) ]
//   h1[h] = leaky(x[b,i]*W1[o,i,h] + b1[o,i,h])
//   h2[k] = leaky(sum_h h1[h]*W2[o,i,k,h] + b2[o,i,k])
//
// R7 = R6 skeleton (i-split waves: wave w owns i-slice [w*16,w*16+16), all
// 4 m-tiles; per W2 fragment 8 MFMAs) plus:
//  (1) b2 / lw*W3 staged once per block into LDS as f16 pairs {lw*w3, b2}
//      -> kills 4 per-iter global dword loads (R6 was latency-bound).
//  (2) x in LDS as duplicated f16 pairs (stride 66, conflict-free reads)
//      -> kills per-m pkrtz dup in the hot loop.
//  (3) epilogue leaky via abs-modifier identity:
//      leaky(v)*w = (0.505*w)*v + (0.495*w)*|v|  -> 2 fma (abs is a free
//      VOP3 input modifier) vs mul+max+fma.
// mfma_f32_16x16x32_f16, f32 accumulation, b2 folded into MFMA C operand.
// Grid o-fastest: blockIdx.x%8 = XCD -> W2 slab XCD-L2-resident.

#define H_   32
#define NI   64
#define NO   64
#define NB   1024
#define ROWS 64     // batch rows per block
#define XSTR 66     // x LDS row stride (uint pairs): 8B-aligned, 2-way banks (free)

typedef float    floatx4 __attribute__((ext_vector_type(4)));
typedef _Float16 halfx8  __attribute__((ext_vector_type(8)));
typedef _Float16 halfx2  __attribute__((ext_vector_type(2)));

union H8 { halfx8 v8; halfx2 v2[4]; unsigned int u[4]; };

__device__ inline float leaky(float v) { return fmaxf(v, 0.01f * v); }

__device__ inline unsigned int pkrtz(float a, float b) {   // (a,b) -> f16x2, RTZ
    return __builtin_bit_cast(unsigned int, __builtin_amdgcn_cvt_pkrtz(a, b));
}

__global__ __launch_bounds__(256, 4)
void kan_kernel(const float* __restrict__ x,  const float* __restrict__ W1,
                const float* __restrict__ b1, const float* __restrict__ W2,
                const float* __restrict__ b2, const float* __restrict__ W3,
                const float* __restrict__ b3, const float* __restrict__ lw,
                const float* __restrict__ bw, float* __restrict__ out)
{
    __shared__ unsigned int xsp[ROWS * XSTR];  // x dup-f16 pairs, 16.9 KB
    __shared__ _Float16 w1s[NI * H_];          // 4 KB
    __shared__ _Float16 b1s[NI * H_];          // 4 KB
    __shared__ unsigned int wbs[NI * H_];      // {lw*w3, b2} f16 pairs, 8 KB
    __shared__ float rc[ROWS];
    __shared__ float part[4][ROWS];            // per-wave i-slice partials, 1 KB

    const int t    = threadIdx.x;
    const int o    = blockIdx.x;               // o fastest -> same-o blocks share XCD
    const int row0 = blockIdx.y * ROWS;

    // ---- stage x tile as duplicated f16 pairs ----
    const float* xsrc = x + (size_t)row0 * NI;
    #pragma unroll
    for (int v = 0; v < 4; ++v) {
        int fe = (v * 256 + t) * 4;            // multiple of 4
        int r = fe >> 6, c = fe & 63;
        float4 xv = *(const float4*)(xsrc + fe);
        uint2 lo = { pkrtz(xv.x, xv.x), pkrtz(xv.y, xv.y) };
        uint2 hi = { pkrtz(xv.z, xv.z), pkrtz(xv.w, xv.w) };
        *(uint2*)(&xsp[r * XSTR + c])     = lo;   // 66r+c even -> 8B aligned
        *(uint2*)(&xsp[r * XSTR + c + 2]) = hi;
    }
    // ---- stage W1/b1 for this o as f16 ----
    const float* w1g = W1 + (size_t)o * NI * H_;
    const float* b1g = b1 + (size_t)o * NI * H_;
    #pragma unroll
    for (int v = 0; v < 2; ++v) {
        int e = (v * 256 + t) * 4;
        float4 a = *(const float4*)(w1g + e);
        float4 c = *(const float4*)(b1g + e);
        uint2 pa = { pkrtz(a.x, a.y), pkrtz(a.z, a.w) };
        uint2 pc = { pkrtz(c.x, c.y), pkrtz(c.z, c.w) };
        *(uint2*)(w1s + e) = pa;
        *(uint2*)(b1s + e) = pc;
    }
    // ---- stage {lw*w3, b2} pairs: 2048 entries, 8 per thread ----
    {
        int e = t * 8;                          // i = e>>5, k = e&31 .. +7
        float l = lw[o * NI + (e >> 5)];
        const float* w3g = W3 + (size_t)o * NI * H_ + e;
        const float* b2g = b2 + (size_t)o * NI * H_ + e;
        float4 wa = *(const float4*)(w3g),     wb2 = *(const float4*)(w3g + 4);
        float4 ba = *(const float4*)(b2g),     bb  = *(const float4*)(b2g + 4);
        uint4 p0 = { pkrtz(l * wa.x, ba.x), pkrtz(l * wa.y, ba.y),
                     pkrtz(l * wa.z, ba.z), pkrtz(l * wa.w, ba.w) };
        uint4 p1 = { pkrtz(l * wb2.x, bb.x), pkrtz(l * wb2.y, bb.y),
                     pkrtz(l * wb2.z, bb.z), pkrtz(l * wb2.w, bb.w) };
        *(uint4*)(&wbs[e])     = p0;
        *(uint4*)(&wbs[e + 4]) = p1;
    }
    __syncthreads();

    // ---- per-row constants: rc[r] = sum_i [ bw*leaky(x) + lw*b3 ] ----
    if (t < ROWS) {
        float s = 0.f;
        const float* bwp = bw + o * NI;
        const float* lp  = lw + o * NI;
        const float* b3p = b3 + o * NI;
        for (int i = 0; i < NI; ++i) {
            halfx2 hx = __builtin_bit_cast(halfx2, xsp[t * XSTR + i]);
            s += bwp[i] * leaky((float)hx[0]) + lp[i] * b3p[i];
        }
        rc[t] = s;
    }

    const int lane = t & 63, wave = t >> 6;
    const int col  = lane & 15;            // MFMA n-index (h2 k-slot) / A m-offset
    const int kh   = lane >> 4;            // contraction quad
    const int koff = kh * 8;
    const int i0   = wave * 16;            // this wave's i-slice

    const float* w2p0 = W2 + ((size_t)(o * NI + i0) * H_ + col) * H_ + koff;
    const float* w2p1 = w2p0 + 16 * H_;
    const halfx2 slope = { (_Float16)0.01f, (_Float16)0.01f };

    floatx4 pacc[4] = { {0,0,0,0}, {0,0,0,0}, {0,0,0,0}, {0,0,0,0} };

    #pragma unroll 4
    for (int ii = 0; ii < 16; ++ii) {
        const int i = i0 + ii;

        // B-frags: W2[o,i, col(+16), koff..+7], f32 -> f16 via pkrtz
        floatx4 a0 = *(const floatx4*)(w2p0);
        floatx4 a1 = *(const floatx4*)(w2p0 + 4);
        floatx4 a2 = *(const floatx4*)(w2p1);
        floatx4 a3 = *(const floatx4*)(w2p1 + 4);
        H8 bf0, bf1;
        bf0.u[0] = pkrtz(a0[0], a0[1]);  bf0.u[1] = pkrtz(a0[2], a0[3]);
        bf0.u[2] = pkrtz(a1[0], a1[1]);  bf0.u[3] = pkrtz(a1[2], a1[3]);
        bf1.u[0] = pkrtz(a2[0], a2[1]);  bf1.u[1] = pkrtz(a2[2], a2[3]);
        bf1.u[2] = pkrtz(a3[0], a3[1]);  bf1.u[3] = pkrtz(a3[2], a3[3]);

        H8 w1v, b1v;
        w1v.v8 = *(const halfx8*)(w1s + i * H_ + koff);
        b1v.v8 = *(const halfx8*)(b1s + i * H_ + koff);

        // per-k constants from LDS: {lw*w3, b2} f16 pairs (broadcast reads)
        halfx2 q0 = __builtin_bit_cast(halfx2, wbs[i * H_ + col]);
        halfx2 q1 = __builtin_bit_cast(halfx2, wbs[i * H_ + col + 16]);
        float w3e0 = (float)q0[0], b2c0 = (float)q0[1];
        float w3e1 = (float)q1[0], b2c1 = (float)q1[1];
        float p0 = 0.505f * w3e0, n0 = 0.495f * w3e0;   // leaky decomposition
        float p1 = 0.505f * w3e1, n1 = 0.495f * w3e1;

        #pragma unroll
        for (int m = 0; m < 4; ++m) {
            halfx2 xx = __builtin_bit_cast(halfx2, xsp[(m * 16 + col) * XSTR + i]);
            H8 af;
            #pragma unroll
            for (int j = 0; j < 4; ++j) {
                halfx2 h = __builtin_elementwise_fma(xx, w1v.v2[j], b1v.v2[j]);
                af.v2[j] = __builtin_elementwise_max(h, h * slope);  // pk leaky
            }
            floatx4 c0 = { b2c0, b2c0, b2c0, b2c0 };   // b2 folded into C
            floatx4 c1 = { b2c1, b2c1, b2c1, b2c1 };
            c0 = __builtin_amdgcn_mfma_f32_16x16x32_f16(af.v8, bf0.v8, c0, 0, 0, 0);
            c1 = __builtin_amdgcn_mfma_f32_16x16x32_f16(af.v8, bf1.v8, c1, 0, 0, 0);
            // pacc += leaky(c)*w3e : leaky(v)*w = (.505w)*v + (.495w)*|v|
            #pragma unroll
            for (int r = 0; r < 4; ++r) {
                pacc[m][r] = fmaf(p0, c0[r],
                             fmaf(n0, fabsf(c0[r]),
                             fmaf(p1, c1[r],
                             fmaf(n1, fabsf(c1[r]), pacc[m][r]))));
            }
        }

        w2p0 += H_ * H_;  w2p1 += H_ * H_;
    }

    // ---- in-wave reduce over the 16 col lanes, deposit i-slice partials ----
    #pragma unroll
    for (int m = 0; m < 4; ++m) {
        #pragma unroll
        for (int r = 0; r < 4; ++r) {
            float v = pacc[m][r];
            v += __shfl_xor(v, 1, 64);
            v += __shfl_xor(v, 2, 64);
            v += __shfl_xor(v, 4, 64);
            v += __shfl_xor(v, 8, 64);
            if (col == 0)
                part[wave][m * 16 + kh * 4 + r] = v;   // C row = (lane>>4)*4+reg
        }
    }
    __syncthreads();

    // ---- cross-wave sum + per-row constant, write out[b,o] ----
    if (t < ROWS) {
        float v = part[0][t] + part[1][t] + part[2][t] + part[3][t] + rc[t];
        out[(size_t)(row0 + t) * NO + o] = v;
    }
}

extern "C" void kernel_launch(void* const* d_in, const int* in_sizes, int n_in,
                              void* d_out, int out_size, void* d_ws, size_t ws_size,
                              hipStream_t stream) {
    const float* x  = (const float*)d_in[0];
    const float* W1 = (const float*)d_in[1];
    const float* b1 = (const float*)d_in[2];
    const float* W2 = (const float*)d_in[3];
    const float* b2 = (const float*)d_in[4];
    const float* W3 = (const float*)d_in[5];
    const float* b3 = (const float*)d_in[6];
    const float* lw = (const float*)d_in[7];
    const float* bw = (const float*)d_in[8];
    float* out = (float*)d_out;

    dim3 grid(NO, NB / ROWS);   // 1024 blocks, o fastest (XCD-local W2)
    kan_kernel<<<grid, dim3(256), 0, stream>>>(x, W1, b1, W2, b2, W3, b3, lw, bw, out);
}